// Round 4
// baseline (99.199 us; speedup 1.0000x reference)
//
#include <hip/hip_runtime.h>

// DiceLoss: input [N=32, C=4, H=512, W=512] f32, target [N,1,H,W] i32.
// softmax over C; since softmax sums to 1, cardinality = 2*HW exactly, so
// loss = 1 - (2/(N*(2*HW+eps))) * sum_{all pixels} probs[target].
//
// Single fused kernel: fixed geometry (2048 blocks x 256 thr x 4 group-iters
// covers all N*HW/4 float4-groups exactly), all 20 vector loads hoisted for
// max memory-level parallelism, last-block-done final reduction (ticket
// counter memset per launch; partials published via device-scope atomics so
// cross-XCD visibility is guaranteed without relying on plain-store flushes).

constexpr int N_   = 32;
constexpr int C_   = 4;
constexpr int HW_  = 512 * 512;                 // 2^18
constexpr float EPSF = 1e-6f;

constexpr int NBLK  = 2048;
constexpr int NTHR  = 256;
constexpr int TOTTH = NBLK * NTHR;              // 524288 threads
constexpr int NGROUPS = N_ * HW_ / 4;           // 2097152 float4-groups
constexpr int NITER = NGROUPS / TOTTH;          // exactly 4
static_assert(NITER * TOTTH == NGROUPS, "geometry must tile exactly");

__global__ __launch_bounds__(NTHR) void dice_fused(
        const float* __restrict__ x,
        const int*   __restrict__ tgt,
        float*       __restrict__ partial,      // d_ws[0 .. NBLK)
        unsigned*    __restrict__ ticket,       // d_ws + NBLK floats
        float*       __restrict__ out) {
    const int tid = blockIdx.x * NTHR + threadIdx.x;

    // ---- phase 1: issue ALL loads (20 x 16B per thread) ----
    float4 v[NITER][C_];
    int4   t4[NITER];
    #pragma unroll
    for (int it = 0; it < NITER; ++it) {
        const int pix = (tid + it * TOTTH) << 2;     // 4 pixels/group
        const int n   = pix >> 18;                   // / HW_
        const int hw  = pix & (HW_ - 1);
        const float* base = x + (size_t)n * (C_ * HW_) + hw;
        #pragma unroll
        for (int c = 0; c < C_; ++c)
            v[it][c] = *reinterpret_cast<const float4*>(base + (size_t)c * HW_);
        t4[it] = *reinterpret_cast<const int4*>(tgt + (size_t)n * HW_ + hw);
    }

    // ---- phase 2: compute (static indices only -> stays in VGPRs) ----
    float acc = 0.f;
    #pragma unroll
    for (int it = 0; it < NITER; ++it) {
        #pragma unroll
        for (int j = 0; j < 4; ++j) {
            float a = reinterpret_cast<const float*>(&v[it][0])[j];
            float b = reinterpret_cast<const float*>(&v[it][1])[j];
            float c = reinterpret_cast<const float*>(&v[it][2])[j];
            float d = reinterpret_cast<const float*>(&v[it][3])[j];
            int   t = reinterpret_cast<const int*>(&t4[it])[j];
            float m  = fmaxf(fmaxf(a, b), fmaxf(c, d));
            float ea = __expf(a - m);
            float eb = __expf(b - m);
            float ec = __expf(c - m);
            float ed = __expf(d - m);
            float denom = (ea + eb) + (ec + ed);
            float et = (t == 0) ? ea : (t == 1) ? eb : (t == 2) ? ec : ed;
            acc += et / denom;
        }
    }

    // ---- phase 3: block reduction (fixed order -> deterministic) ----
    #pragma unroll
    for (int off = 32; off > 0; off >>= 1)
        acc += __shfl_down(acc, off, 64);

    __shared__ float wsum[NTHR / 64];
    __shared__ int   lastFlag;
    const int lane = threadIdx.x & 63;
    const int wid  = threadIdx.x >> 6;
    if (lane == 0) wsum[wid] = acc;
    __syncthreads();

    if (threadIdx.x == 0) {
        float bs = (wsum[0] + wsum[1]) + (wsum[2] + wsum[3]);
        // publish partial via device-scope atomic (coherent across XCDs)
        atomicExch(reinterpret_cast<unsigned*>(&partial[blockIdx.x]),
                   __float_as_uint(bs));
        __threadfence();
        unsigned old = atomicAdd(ticket, 1u);
        lastFlag = (old == (unsigned)(NBLK - 1));
    }
    __syncthreads();

    // ---- phase 4: last block reduces all partials in fixed order ----
    if (lastFlag) {
        __threadfence();
        float a = 0.f;
        #pragma unroll
        for (int r = 0; r < NBLK / NTHR; ++r) {
            int i = r * NTHR + threadIdx.x;  // fixed order per thread
            a += __uint_as_float(
                atomicAdd(reinterpret_cast<unsigned*>(&partial[i]), 0u));
        }
        #pragma unroll
        for (int off = 32; off > 0; off >>= 1)
            a += __shfl_down(a, off, 64);
        if (lane == 0) wsum[wid] = a;
        __syncthreads();
        if (threadIdx.x == 0) {
            float S    = (wsum[0] + wsum[1]) + (wsum[2] + wsum[3]);
            float card = 2.0f * (float)HW_ + EPSF;
            out[0] = 1.0f - 2.0f * S / ((float)N_ * card);
        }
    }
}

extern "C" void kernel_launch(void* const* d_in, const int* in_sizes, int n_in,
                              void* d_out, int out_size, void* d_ws, size_t ws_size,
                              hipStream_t stream) {
    const float* x   = (const float*)d_in[0];
    const int*   tgt = (const int*)d_in[1];
    float*       out = (float*)d_out;

    float*    partial = (float*)d_ws;
    unsigned* ticket  = (unsigned*)((char*)d_ws + (size_t)NBLK * sizeof(float));

    // reset ticket each call (ws is poisoned once and never re-poisoned;
    // memset nodes are graph-capture-legal — the harness uses them itself)
    hipMemsetAsync(ticket, 0, sizeof(unsigned), stream);

    dice_fused<<<NBLK, NTHR, 0, stream>>>(x, tgt, partial, ticket, out);
}